// Round 1
// 189.787 us; speedup vs baseline: 1.1057x; 1.1057x over previous
//
#include <hip/hip_runtime.h>
#include <hip/hip_bf16.h>
#include <math.h>

#define BB 8
#define NN 2048
#define DD 1024
#define LL 128
#define MM (BB*NN)   // 16384

typedef _Float16 half8 __attribute__((ext_vector_type(8)));
typedef _Float16 half4 __attribute__((ext_vector_type(4)));
typedef __attribute__((ext_vector_type(4))) float floatx4;

__device__ __forceinline__ void glds16(const void* g, void* l) {
    __builtin_amdgcn_global_load_lds(
        (const __attribute__((address_space(1))) unsigned int*)g,
        (__attribute__((address_space(3))) unsigned int*)l, 16, 0, 0);
}

#define CFENCE() asm volatile("" ::: "memory")
#define BARRIER() do { CFENCE(); __builtin_amdgcn_s_barrier(); CFENCE(); } while (0)

// fast tanh: 1 - 2/(e^{2x}+1); saturates correctly for |x| large, ~1e-6 abs err
__device__ __forceinline__ float ftanh(float x) {
    float e = __expf(2.0f * x);
    return 1.0f - 2.0f * __builtin_amdgcn_rcpf(e + 1.0f);
}

// ---------------- fused preprocessing: e_j -> fp16, Wk -> fp16, q = e_i @ Wq^T
__global__ __launch_bounds__(256) void prep_kernel(const float* __restrict__ e_j,
                                                   _Float16* __restrict__ eh,
                                                   const float* __restrict__ Wk,
                                                   _Float16* __restrict__ wh,
                                                   const float* __restrict__ e_i,
                                                   const float* __restrict__ Wq,
                                                   float* __restrict__ q) {
    __shared__ float us[BB][DD];   // 32 KB, used only by the q branch
    int blk = blockIdx.x;
    int tid = threadIdx.x;
    if (blk < 8192) {
        int i = blk * 256 + tid;
        const float4* xp = (const float4*)e_j + (size_t)i * 2;
        float4 v0 = xp[0], v1 = xp[1];
        half8 h;
        h[0] = (_Float16)v0.x; h[1] = (_Float16)v0.y;
        h[2] = (_Float16)v0.z; h[3] = (_Float16)v0.w;
        h[4] = (_Float16)v1.x; h[5] = (_Float16)v1.y;
        h[6] = (_Float16)v1.z; h[7] = (_Float16)v1.w;
        *(half8*)(eh + (size_t)i * 8) = h;
    } else if (blk < 8704) {
        int i = (blk - 8192) * 256 + tid;
        const float4* xp = (const float4*)Wk + (size_t)i * 2;
        float4 v0 = xp[0], v1 = xp[1];
        half8 h;
        h[0] = (_Float16)v0.x; h[1] = (_Float16)v0.y;
        h[2] = (_Float16)v0.z; h[3] = (_Float16)v0.w;
        h[4] = (_Float16)v1.x; h[5] = (_Float16)v1.y;
        h[6] = (_Float16)v1.z; h[7] = (_Float16)v1.w;
        *(half8*)(wh + (size_t)i * 8) = h;
    } else {
        for (int i = tid; i < BB * DD / 4; i += 256)
            ((float4*)&us[0][0])[i] = ((const float4*)e_i)[i];
        __syncthreads();
        int w = tid >> 6, lane = tid & 63;
        int d = (blk - 8704) * 4 + w;
        float acc[8] = {0.f, 0.f, 0.f, 0.f, 0.f, 0.f, 0.f, 0.f};
        for (int e0 = 0; e0 < DD; e0 += 256) {
            float4 wv = *(const float4*)&Wq[(size_t)d * DD + e0 + lane * 4];
            #pragma unroll
            for (int r = 0; r < 8; ++r) {
                float4 uv = *(const float4*)&us[r][e0 + lane * 4];
                acc[r] += wv.x * uv.x + wv.y * uv.y + wv.z * uv.z + wv.w * uv.w;
            }
        }
        #pragma unroll
        for (int r = 0; r < 8; ++r) {
            float s = acc[r];
            #pragma unroll
            for (int off = 32; off; off >>= 1) s += __shfl_down(s, off, 64);
            if (lane == 0) q[r * DD + d] = s;
        }
    }
}

// ---------------- sigma: 256x256-tile, 8-wave, quad-buffered BK=32 pipeline
// (T1 XCD swizzle + T2 XOR LDS swizzle + T3/T4 counted vmcnt + T5 setprio)
// fused epilogue: sig_part[c][row] = sum_col tanh(S+q)*omega  (4 col-slices)
__global__ __launch_bounds__(512, 2) void sigma256(const _Float16* __restrict__ eh,
                                                   const _Float16* __restrict__ wh,
                                                   const float* __restrict__ q,
                                                   const float* __restrict__ omega,
                                                   float* __restrict__ sig_part) // [4][MM]
{
    __shared__ _Float16 As[4][256][32];   // 64 KB (4 K-tile buffers)
    __shared__ _Float16 Bs[4][256][32];   // 64 KB

    const int tid  = threadIdx.x;
    const int lane = tid & 63;
    const int wid  = tid >> 6;          // 0..7
    const int wr   = wid >> 2;          // 0..1  (M split: 128 rows/wave)
    const int wc   = wid & 3;           // 0..3  (N split: 64 cols/wave)
    const int c15  = lane & 15, quad = lane >> 4;

    // XCD-chunked bijective swizzle: 256 wgs, 32 per XCD, col-major chunks
    const int wgid   = (blockIdx.x & 7) * 32 + (blockIdx.x >> 3);
    const int colBlk = wgid >> 6;        // 0..3
    const int rowBlk = wgid & 63;        // 0..63
    const int row0   = rowBlk * 256;
    const int col0   = colBlk * 256;
    const int b      = row0 / NN;

    // staging: linear LDS dest (glds16 requirement), swizzle folded into the
    // per-lane GLOBAL source column: sub = (lane&3) ^ ((lane>>3)&3)
    const int srow = wid * 16 + (lane >> 2);                 // 0..127
    const int ssub = ((lane & 3) ^ ((lane >> 3) & 3)) * 8;   // swizzled k-slot
    const _Float16* gA = eh + (size_t)(row0 + srow) * DD + ssub;
    const _Float16* gB = wh + (size_t)(col0 + srow) * DD + ssub;
    char* const ldsA0 = (char*)&As[0][0][0] + wid * 1024;
    char* const ldsB0 = (char*)&Bs[0][0][0] + wid * 1024;

#define STAGE_A(kt) do { int _bi = (kt) & 3; int _k0 = (kt) * 32;                  \
        glds16(gA + _k0,                    ldsA0 + _bi * 16384);                  \
        glds16(gA + (size_t)128 * DD + _k0, ldsA0 + _bi * 16384 + 8192); } while (0)
#define STAGE_B(kt) do { int _bi = (kt) & 3; int _k0 = (kt) * 32;                  \
        glds16(gB + _k0,                    ldsB0 + _bi * 16384);                  \
        glds16(gB + (size_t)128 * DD + _k0, ldsB0 + _bi * 16384 + 8192); } while (0)

    const char* const Abase = (const char*)&As[0][0][0];
    const char* const Bbase = (const char*)&Bs[0][0][0];
// swizzled fragment read: row stride 64B, XOR row bits 1-2 into the 16B slot
#define FRAG(base, bi, row, qd) \
    (*(const half8*)((base) + (bi) * 16384 + (row) * 64 + ((((qd) ^ (((row) >> 1) & 3))) << 4)))

    floatx4 acc[8][4];
    #pragma unroll
    for (int m = 0; m < 8; ++m)
        #pragma unroll
        for (int n = 0; n < 4; ++n) acc[m][n] = (floatx4){0.f, 0.f, 0.f, 0.f};

    // prologue: stage tiles 0,1,2 (12 vmem insts); vmcnt(8) => tile 0 landed
    STAGE_A(0); STAGE_B(0);
    STAGE_A(1); STAGE_B(1);
    STAGE_A(2); STAGE_B(2);
    asm volatile("s_waitcnt vmcnt(8)" ::: "memory");
    BARRIER();

// one K-tile = 2 phases; per phase: 4-8 ds_read_b128 | 2 glds16 | bar | 16 MFMA | bar.
// vmcnt ledger at tile end: issued 12+4(t+1), vmcnt(8) => tiles 0..t+1 landed.
#define TILE_BODY(t_, DO_STAGE, VMW)                                              \
    {                                                                             \
        const int bi = (t_) & 3;                                                  \
        half8 a[4], bb[4];                                                        \
        _Pragma("unroll")                                                         \
        for (int m = 0; m < 4; ++m) a[m]  = FRAG(Abase, bi, wr * 128 + m * 16 + c15, quad); \
        _Pragma("unroll")                                                         \
        for (int n = 0; n < 4; ++n) bb[n] = FRAG(Bbase, bi, wc * 64  + n * 16 + c15, quad); \
        if (DO_STAGE) STAGE_A((t_) + 3);                                          \
        BARRIER();                                                                \
        __builtin_amdgcn_s_setprio(1);                                            \
        _Pragma("unroll")                                                         \
        for (int m = 0; m < 4; ++m)                                               \
            _Pragma("unroll")                                                     \
            for (int n = 0; n < 4; ++n)                                           \
                acc[m][n] = __builtin_amdgcn_mfma_f32_16x16x32_f16(a[m], bb[n], acc[m][n], 0, 0, 0); \
        __builtin_amdgcn_s_setprio(0);                                            \
        BARRIER();                                                                \
        _Pragma("unroll")                                                         \
        for (int m = 0; m < 4; ++m) a[m] = FRAG(Abase, bi, wr * 128 + 64 + m * 16 + c15, quad); \
        if (DO_STAGE) STAGE_B((t_) + 3);                                          \
        BARRIER();                                                                \
        __builtin_amdgcn_s_setprio(1);                                            \
        _Pragma("unroll")                                                         \
        for (int m = 0; m < 4; ++m)                                               \
            _Pragma("unroll")                                                     \
            for (int n = 0; n < 4; ++n)                                           \
                acc[4 + m][n] = __builtin_amdgcn_mfma_f32_16x16x32_f16(a[m], bb[n], acc[4 + m][n], 0, 0, 0); \
        __builtin_amdgcn_s_setprio(0);                                            \
        asm volatile("s_waitcnt vmcnt(" #VMW ")" ::: "memory");                   \
        BARRIER();                                                                \
    }

    for (int t = 0; t < 29; ++t) TILE_BODY(t, 1, 8)   // stages tiles 3..31
    TILE_BODY(29, 0, 4)
    TILE_BODY(30, 0, 0)
    TILE_BODY(31, 0, 0)

    // ---- fused epilogue: part[row] = sum_n tanh(acc+q)*omega over this wave's 64 cols
    float part[8][4];
    #pragma unroll
    for (int m = 0; m < 8; ++m)
        #pragma unroll
        for (int r = 0; r < 4; ++r) part[m][r] = 0.f;

    #pragma unroll
    for (int n = 0; n < 4; ++n) {
        int col = col0 + wc * 64 + n * 16 + c15;
        float qv = q[b * DD + col];
        float om = omega[col];
        #pragma unroll
        for (int m = 0; m < 8; ++m)
            #pragma unroll
            for (int r = 0; r < 4; ++r)
                part[m][r] += ftanh(acc[m][n][r] + qv) * om;
    }

    float (*red)[4] = (float(*)[4])&As[0][0][0];   // 4 KB, reuse dead A-buffer
    #pragma unroll
    for (int m = 0; m < 8; ++m)
        #pragma unroll
        for (int r = 0; r < 4; ++r) {
            float s = part[m][r];
            s += __shfl_xor(s, 1, 64);
            s += __shfl_xor(s, 2, 64);
            s += __shfl_xor(s, 4, 64);
            s += __shfl_xor(s, 8, 64);
            if (c15 == 0) red[wr * 128 + m * 16 + quad * 4 + r][wc] = s;
        }
    __syncthreads();
    if (tid < 256)
        sig_part[(size_t)colBlk * MM + row0 + tid] =
            red[tid][0] + red[tid][1] + red[tid][2] + red[tid][3];
#undef TILE_BODY
#undef FRAG
#undef STAGE_A
#undef STAGE_B
}

// ---------------- per-b softmax-style weights (64 blocks: 8 per b, full stats each)
__global__ __launch_bounds__(256) void softmax_k(const float* __restrict__ sig_part,
                                                 const float* __restrict__ imp,
                                                 float* __restrict__ a_ij) {
    int b = blockIdx.x >> 3, slice = blockIdx.x & 7;
    int tid = threadIdx.x;
    __shared__ float red[256];
    float sv[8];
    float m = -1e30f;
    #pragma unroll
    for (int p = 0; p < 8; ++p) {
        int n = p * 256 + tid;
        float s = 0.f;
        #pragma unroll
        for (int db = 0; db < 4; ++db) s += sig_part[db * MM + b * NN + n];
        sv[p] = s;
        m = fmaxf(m, s);
    }
    red[tid] = m; __syncthreads();
    for (int off = 128; off; off >>= 1) {
        if (tid < off) red[tid] = fmaxf(red[tid], red[tid + off]);
        __syncthreads();
    }
    m = red[0]; __syncthreads();
    float sum = 0.f;
    #pragma unroll
    for (int p = 0; p < 8; ++p) sum += expf(sv[p] - m);
    red[tid] = sum; __syncthreads();
    for (int off = 128; off; off >>= 1) {
        if (tid < off) red[tid] += red[tid + off];
        __syncthreads();
    }
    float inv = 1.f / (red[0] + 1e-9f * expf(-m));
    int n = slice * 256 + tid;
    a_ij[b * NN + n] = imp[b * NN + n] * expf(sv[slice] - m) * inv;
}

// ---------------- u partials from fp16 e_j: 1024 blocks, disjoint writes
__global__ __launch_bounds__(256) void u_kernel(const float* __restrict__ a_ij,
                                                const _Float16* __restrict__ eh,
                                                float* __restrict__ u_part) {
    int b = blockIdx.x >> 7, nc = blockIdx.x & 127;
    int t = threadIdx.x;
    float4 acc = {0.f, 0.f, 0.f, 0.f};
    const _Float16* base = eh + ((size_t)(b * NN + nc * 16)) * DD + t * 4;
    const float* ap = a_ij + b * NN + nc * 16;
    #pragma unroll
    for (int n = 0; n < 16; ++n) {
        float a = ap[n];
        half4 v = *(const half4*)(base + (size_t)n * DD);
        acc.x += a * (float)v[0]; acc.y += a * (float)v[1];
        acc.z += a * (float)v[2]; acc.w += a * (float)v[3];
    }
    *(float4*)(u_part + ((size_t)nc * BB + b) * DD + t * 4) = acc;
}

// ---------------- u[b,e] = sum over 128 partials
__global__ __launch_bounds__(256) void ureduce(const float* __restrict__ u_part,
                                               float* __restrict__ u) {
    int i = blockIdx.x * 256 + threadIdx.x;   // < 8192
    float s = 0.f;
    #pragma unroll 8
    for (int nc = 0; nc < 128; ++nc) s += u_part[(size_t)nc * BB * DD + i];
    u[i] = s;
}

// ---------------- A = X @ W^T with X cached in LDS; W read once (256 blocks)
__global__ __launch_bounds__(256) void rowdot8(const float* __restrict__ X,
                                               const float* __restrict__ W,
                                               float* __restrict__ out) {
    __shared__ float us[BB][DD];
    int tid = threadIdx.x;
    for (int i = tid; i < BB * DD / 4; i += 256)
        ((float4*)&us[0][0])[i] = ((const float4*)X)[i];
    __syncthreads();
    int w = tid >> 6, lane = tid & 63;
    int d = blockIdx.x * 4 + w;
    float acc[8] = {0.f, 0.f, 0.f, 0.f, 0.f, 0.f, 0.f, 0.f};
    for (int e0 = 0; e0 < DD; e0 += 256) {
        float4 wv = *(const float4*)&W[(size_t)d * DD + e0 + lane * 4];
        #pragma unroll
        for (int r = 0; r < 8; ++r) {
            float4 uv = *(const float4*)&us[r][e0 + lane * 4];
            acc[r] += wv.x * uv.x + wv.y * uv.y + wv.z * uv.z + wv.w * uv.w;
        }
    }
    #pragma unroll
    for (int r = 0; r < 8; ++r) {
        float s = acc[r];
        #pragma unroll
        for (int off = 32; off; off >>= 1) s += __shfl_down(s, off, 64);
        if (lane == 0) out[r * DD + d] = s;
    }
}

// ---------------- outputs: A, A_lk = A*R, A_l = A
__global__ __launch_bounds__(256) void out_kernel(const float* __restrict__ A,
                                                  const float* __restrict__ Rlk,
                                                  float* __restrict__ out) {
    int i = blockIdx.x * 256 + threadIdx.x;
    int d = i & (DD - 1);
    int l = (i >> 10) & (LL - 1);
    int b = i >> 17;
    out[BB * DD + i] = A[b * DD + d] * Rlk[l * DD + d];
    if (i < BB * DD) {
        out[i] = A[i];
        out[BB * DD + BB * LL * DD + i] = A[i];
    }
}

extern "C" void kernel_launch(void* const* d_in, const int* in_sizes, int n_in,
                              void* d_out, int out_size, void* d_ws, size_t ws_size,
                              hipStream_t stream) {
    const float* e_i   = (const float*)d_in[0];
    const float* e_j   = (const float*)d_in[1];
    const float* imp   = (const float*)d_in[2];
    const float* Rlk   = (const float*)d_in[3];
    const float* Wq    = (const float*)d_in[4];
    const float* Wk    = (const float*)d_in[5];
    const float* Wv    = (const float*)d_in[6];
    const float* omega = (const float*)d_in[7];
    float* out = (float*)d_out;
    float* ws  = (float*)d_ws;

    float* q    = ws;               // 8192
    float* sigp = ws + 8192;        // 65536 used (region holds 131072)
    float* a_ij = ws + 139264;      // 16384 (head reused as Abuf)
    float* u    = ws + 155648;      // 8192
    _Float16* eh = (_Float16*)(ws + 172032);      // MM*DD halfs = 32 MB
    _Float16* wh = eh + (size_t)MM * DD;          // 2 MB
    float* u_part = (float*)(wh + (size_t)DD * DD);  // 4 MB

    // 1) e_j -> fp16, Wk -> fp16, q = e_i @ Wq^T (Wq read once)
    prep_kernel<<<8960, 256, 0, stream>>>(e_j, eh, Wk, wh, e_i, Wq, q);

    // 2) sigma partials: 256^2-tile counted-vmcnt pipeline with fused tanh-omega
    sigma256<<<dim3(256), 512, 0, stream>>>(eh, wh, q, omega, sigp);

    // 3) a_ij
    softmax_k<<<64, 256, 0, stream>>>(sigp, imp, a_ij);

    // 4) u partials (no atomics) from fp16 e_j, then reduce
    u_kernel<<<1024, 256, 0, stream>>>(a_ij, eh, u_part);
    ureduce<<<32, 256, 0, stream>>>(u_part, u);

    // 5) A = u @ Wv^T (Wv read once; Abuf = a_ij head)
    rowdot8<<<256, 256, 0, stream>>>(u, Wv, a_ij);

    // 6) outputs
    out_kernel<<<(BB * LL * DD) / 256, 256, 0, stream>>>(a_ij, Rlk, out);
}